// Round 2
// baseline (659.204 us; speedup 1.0000x reference)
//
#include <hip/hip_runtime.h>
#include <hip/hip_bf16.h>

// MinGRU fused: Y = scan of h = a*h + (1-a)*g along L, with
//   a = sigmoid(-(x@Wz^T+bz)),  g = g_fn(x@Wn^T+bn)
// B=4, L=4096, D=2048.

#define D_DIM 2048
#define B_DIM 4
#define L_DIM 4096
#define M_DIM (B_DIM * L_DIM)      // 16384 GEMM rows
#define KDIM  D_DIM                // GEMM K
#define NCOL  (2 * D_DIM)          // 4096 GEMM cols: [0,2048)=z-logits, [2048,4096)=n
#define CHUNK 64
#define NCHUNK (L_DIM / CHUNK)     // 64

typedef __bf16 bf16x8 __attribute__((ext_vector_type(8)));
typedef float  f32x4  __attribute__((ext_vector_type(4)));

__device__ __forceinline__ unsigned short f2bf(float f) {
  unsigned int u = __float_as_uint(f);
  u += 0x7FFFu + ((u >> 16) & 1u);   // RNE
  return (unsigned short)(u >> 16);
}
__device__ __forceinline__ float bf2f(unsigned short s) {
  return __uint_as_float(((unsigned int)s) << 16);
}

__device__ __forceinline__ void load_lds16(const void* g, void* l) {
  __builtin_amdgcn_global_load_lds(
      (const __attribute__((address_space(1))) void*)g,
      (__attribute__((address_space(3))) void*)l, 16, 0, 0);
}

// ---------------- cast x, Wz, Wn -> bf16 (xb[M][K], wb[NCOL][K]) ----------------
__global__ __launch_bounds__(256) void cast_inputs(
    const float* __restrict__ x, const float* __restrict__ Wz,
    const float* __restrict__ Wn,
    unsigned short* __restrict__ xb, unsigned short* __restrict__ wb) {
  const size_t MK4 = (size_t)M_DIM * KDIM / 4;   // 8388608 groups
  const size_t DD4 = (size_t)D_DIM * D_DIM / 4;  // 1048576 groups
  size_t i = (size_t)blockIdx.x * 256 + threadIdx.x;
  const float4* src; ushort4* dst; size_t off;
  if (i < MK4)            { src = (const float4*)x;  dst = (ushort4*)xb; off = i; }
  else if (i < MK4 + DD4) { src = (const float4*)Wz; dst = (ushort4*)wb; off = i - MK4; }
  else                    { src = (const float4*)Wn;
                            dst = (ushort4*)(wb + (size_t)D_DIM * D_DIM);
                            off = i - MK4 - DD4; }
  float4 v = src[off];
  ushort4 o;
  o.x = f2bf(v.x); o.y = f2bf(v.y); o.z = f2bf(v.z); o.w = f2bf(v.w);
  dst[off] = o;
}

// ---------------- GEMM (m97-style 128x128, BK=32) + fused epilogue ----------------
// out(gr,gc) = sum_k xb[gr][k]*wb[gc][k]  (+bias), then transform, store bf16.
__global__ __launch_bounds__(256) void gemm_fused(
    const unsigned short* __restrict__ xb, const unsigned short* __restrict__ wb,
    const float* __restrict__ bzv, const float* __restrict__ bnv,
    unsigned short* __restrict__ Ab, unsigned short* __restrict__ Gb) {
  __shared__ unsigned short As[128 * 32];
  __shared__ unsigned short Bs[128 * 32];
  const int t = threadIdx.x;
  const int w = t >> 6, lane = t & 63;
  const int ntile = blockIdx.x;   // 0..31  (col tiles; 0..15 = z half, 16..31 = n half)
  const int mtile = blockIdx.y;   // 0..127 (row tiles)
  const unsigned short* aSrc = xb + (size_t)mtile * 128 * KDIM;
  const unsigned short* bSrc = wb + (size_t)ntile * 128 * KDIM;

  f32x4 acc[4][4] = {};
  const int waveM = (w >> 1) * 64;
  const int waveN = (w & 1) * 64;
  // staging: chunk c (16B) -> LDS shorts [c*8, c*8+8); row=c>>2, colseg=c&3
  const int r0 = t >> 2, r1 = (t + 256) >> 2, sseg = t & 3;

  for (int k0 = 0; k0 < KDIM; k0 += 32) {
    load_lds16(aSrc + (size_t)r0 * KDIM + k0 + sseg * 8, As + (size_t)t * 8);
    load_lds16(aSrc + (size_t)r1 * KDIM + k0 + sseg * 8, As + (size_t)(t + 256) * 8);
    load_lds16(bSrc + (size_t)r0 * KDIM + k0 + sseg * 8, Bs + (size_t)t * 8);
    load_lds16(bSrc + (size_t)r1 * KDIM + k0 + sseg * 8, Bs + (size_t)(t + 256) * 8);
    __syncthreads();   // drains vmcnt -> staged data visible

    bf16x8 aF[4], bF[4];
#pragma unroll
    for (int m = 0; m < 4; ++m)
      aF[m] = *(const bf16x8*)&As[(waveM + m * 16 + (lane & 15)) * 32 + (lane >> 4) * 8];
#pragma unroll
    for (int n = 0; n < 4; ++n)
      bF[n] = *(const bf16x8*)&Bs[(waveN + n * 16 + (lane & 15)) * 32 + (lane >> 4) * 8];
#pragma unroll
    for (int m = 0; m < 4; ++m)
#pragma unroll
      for (int n = 0; n < 4; ++n)
        acc[m][n] = __builtin_amdgcn_mfma_f32_16x16x32_bf16(aF[m], bF[n], acc[m][n], 0, 0, 0);
    __syncthreads();   // protect LDS before next stage
  }

  // epilogue: C/D layout col=lane&15, row=(lane>>4)*4+j  [guide §3, m89-verified]
  const bool isZ = (ntile < 16);
  const int colBase = ntile * 128 + waveN;
  const int rowBase = mtile * 128 + waveM;
#pragma unroll
  for (int n = 0; n < 4; ++n) {
    const int gc = colBase + n * 16 + (lane & 15);
    const int dcol = isZ ? gc : (gc - D_DIM);
    const float bias = isZ ? bzv[dcol] : bnv[dcol];
#pragma unroll
    for (int m = 0; m < 4; ++m) {
      const int gr = rowBase + m * 16 + ((lane >> 4) << 2);
#pragma unroll
      for (int j = 0; j < 4; ++j) {
        const float val = acc[m][n][j] + bias;
        const size_t off = (size_t)(gr + j) * D_DIM + dcol;
        if (isZ) {
          // a = 1 - sigmoid(k) = sigmoid(-k)
          Ab[off] = f2bf(1.0f / (1.0f + __expf(val)));
        } else {
          // g(n) = n+0.5 (n>=0) else sigmoid(n)
          Gb[off] = f2bf(val >= 0.0f ? val + 0.5f : 1.0f / (1.0f + __expf(-val)));
        }
      }
    }
  }
}

// ---------------- blocked scan over L ----------------
// pass1: per (b,chunk,d) compute (A,V) with h_end = A*h_start + V
__global__ __launch_bounds__(256) void scan_pass1(
    const unsigned short* __restrict__ Ab, const unsigned short* __restrict__ Gb,
    float* __restrict__ SA, float* __restrict__ SV) {
  const int tid = blockIdx.x * 256 + threadIdx.x;       // B*NCHUNK*D = 524288
  const int d = tid & (D_DIM - 1);
  const int c = (tid >> 11) & (NCHUNK - 1);
  const int b = tid >> 17;
  size_t base = ((size_t)b * L_DIM + (size_t)c * CHUNK) * D_DIM + d;
  float Acc = 1.0f, Vcc = 0.0f;
#pragma unroll 8
  for (int i = 0; i < CHUNK; ++i) {
    float a = bf2f(Ab[base + (size_t)i * D_DIM]);
    float g = bf2f(Gb[base + (size_t)i * D_DIM]);
    Vcc = a * Vcc + (1.0f - a) * g;
    Acc *= a;
  }
  SA[tid] = Acc;
  SV[tid] = Vcc;
}

// pass2: sequential over chunks, store per-chunk starting h
__global__ __launch_bounds__(256) void scan_pass2(
    const float* __restrict__ SA, const float* __restrict__ SV,
    float* __restrict__ H0) {
  const int tid = blockIdx.x * 256 + threadIdx.x;       // B*D = 8192
  const int d = tid & (D_DIM - 1);
  const int b = tid >> 11;
  float h = 0.5f;
  for (int c = 0; c < NCHUNK; ++c) {
    size_t idx = ((size_t)b * NCHUNK + c) * D_DIM + d;
    H0[idx] = h;
    h = SA[idx] * h + SV[idx];
  }
}

// pass3: recompute within chunk from correct h_start, write fp32 output
__global__ __launch_bounds__(256) void scan_pass3(
    const unsigned short* __restrict__ Ab, const unsigned short* __restrict__ Gb,
    const float* __restrict__ H0, float* __restrict__ out) {
  const int tid = blockIdx.x * 256 + threadIdx.x;
  const int d = tid & (D_DIM - 1);
  const int c = (tid >> 11) & (NCHUNK - 1);
  const int b = tid >> 17;
  size_t base = ((size_t)b * L_DIM + (size_t)c * CHUNK) * D_DIM + d;
  float h = H0[tid];
#pragma unroll 8
  for (int i = 0; i < CHUNK; ++i) {
    float a = bf2f(Ab[base + (size_t)i * D_DIM]);
    float g = bf2f(Gb[base + (size_t)i * D_DIM]);
    h = a * h + (1.0f - a) * g;
    out[base + (size_t)i * D_DIM] = h;
  }
}

extern "C" void kernel_launch(void* const* d_in, const int* in_sizes, int n_in,
                              void* d_out, int out_size, void* d_ws, size_t ws_size,
                              hipStream_t stream) {
  const float* x  = (const float*)d_in[0];
  const float* Wz = (const float*)d_in[1];
  const float* bz = (const float*)d_in[2];
  const float* Wn = (const float*)d_in[3];
  const float* bn = (const float*)d_in[4];
  float* out = (float*)d_out;

  char* ws = (char*)d_ws;
  // workspace layout (total ~224.4 MB)
  unsigned short* xb = (unsigned short*)(ws);                       // 67108864 B
  unsigned short* wb = (unsigned short*)(ws + 67108864);            // 16777216 B
  unsigned short* Ab = (unsigned short*)(ws + 83886080);            // 67108864 B
  unsigned short* Gb = (unsigned short*)(ws + 150994944);           // 67108864 B
  float* SA = (float*)(ws + 218103808);                             // 2097152 B
  float* SV = (float*)(ws + 220200960);                             // 2097152 B
  float* H0 = (float*)(ws + 222298112);                             // 2097152 B

  // 1) cast to bf16: (M*K + 2*D*D)/4 groups = 10485760 -> 40960 blocks
  cast_inputs<<<40960, 256, 0, stream>>>(x, Wz, Wn, xb, wb);
  // 2) fused GEMM: grid 32 col-tiles x 128 row-tiles
  gemm_fused<<<dim3(32, 128), 256, 0, stream>>>(xb, wb, bz, bn, Ab, Gb);
  // 3) blocked scan
  scan_pass1<<<2048, 256, 0, stream>>>(Ab, Gb, SA, SV);
  scan_pass2<<<32, 256, 0, stream>>>(SA, SV, H0);
  scan_pass3<<<2048, 256, 0, stream>>>(Ab, Gb, H0, out);
}

// Round 6
// 576.632 us; speedup vs baseline: 1.1432x; 1.1432x over previous
//
#include <hip/hip_runtime.h>
#include <hip/hip_bf16.h>

// MinGRU fused: Y = scan of h = a*h + (1-a)*g along L, with
//   a = sigmoid(-(x@Wz^T+bz)),  g = g_fn(x@Wn^T+bn)
// B=4, L=4096, D=2048.
// GEMM: 256x256 tile, BK=64, 8-phase schedule (T2+T3+T4+T5).

#define D_DIM 2048
#define B_DIM 4
#define L_DIM 4096
#define M_DIM (B_DIM * L_DIM)      // 16384 GEMM rows
#define KDIM  D_DIM                // GEMM K
#define NT    (KDIM / 64)          // 32 K-tiles
#define CHUNK 64
#define NCHUNK (L_DIM / CHUNK)     // 64

typedef __bf16 bf16x8 __attribute__((ext_vector_type(8)));
typedef float  f32x4  __attribute__((ext_vector_type(4)));

__device__ __forceinline__ unsigned short f2bf(float f) {
  unsigned int u = __float_as_uint(f);
  u += 0x7FFFu + ((u >> 16) & 1u);   // RNE
  return (unsigned short)(u >> 16);
}
__device__ __forceinline__ float bf2f(unsigned short s) {
  return __uint_as_float(((unsigned int)s) << 16);
}

__device__ __forceinline__ void load_lds16(const void* g, void* l) {
  __builtin_amdgcn_global_load_lds(
      (const __attribute__((address_space(1))) void*)g,
      (__attribute__((address_space(3))) void*)l, 16, 0, 0);
}

// ---------------- cast x, Wz, Wn -> bf16 (xb[M][K], wb[NCOL][K]) ----------------
__global__ __launch_bounds__(256) void cast_inputs(
    const float* __restrict__ x, const float* __restrict__ Wz,
    const float* __restrict__ Wn,
    unsigned short* __restrict__ xb, unsigned short* __restrict__ wb) {
  const size_t MK4 = (size_t)M_DIM * KDIM / 4;   // 8388608 groups
  const size_t DD4 = (size_t)D_DIM * D_DIM / 4;  // 1048576 groups
  size_t i = (size_t)blockIdx.x * 256 + threadIdx.x;
  const float4* src; ushort4* dst; size_t off;
  if (i < MK4)            { src = (const float4*)x;  dst = (ushort4*)xb; off = i; }
  else if (i < MK4 + DD4) { src = (const float4*)Wz; dst = (ushort4*)wb; off = i - MK4; }
  else                    { src = (const float4*)Wn;
                            dst = (ushort4*)(wb + (size_t)D_DIM * D_DIM);
                            off = i - MK4 - DD4; }
  float4 v = src[off];
  ushort4 o;
  o.x = f2bf(v.x); o.y = f2bf(v.y); o.z = f2bf(v.z); o.w = f2bf(v.w);
  dst[off] = o;
}

// ---------------- GEMM: 256x256 8-phase (T2 swizzle + counted vmcnt + setprio) ----
// LDS per buf: A0,A1,B0,B1 regions of [128 rows][64 cols] bf16 (16KB each).
// Swizzle: 16B-slot index ^= (row&7), applied to global SOURCE on stage and to
// ds_read address on read (both-sides involution, rule 21).
// Schedule per group U (computes K-tile U from buf[U&1], 4 phases):
//  g1: read aF(qm0)+bF(qn0), stage A0(U+1)->buf[!cur]; MFMA quad(0,0)
//  g2: read bF(qn1),          stage A1(U+1)->buf[!cur]; MFMA quad(0,1)
//  g3: read aF(qm1),          stage B0(U+2)->buf[cur];  MFMA quad(1,0)
//  g4:                        stage B1(U+2)->buf[cur];  vmcnt(4); MFMA quad(1,1)
// vmcnt(4) leaves only B0/B1(U+2) in flight => tile U+1 fully landed before
// the end-of-phase barrier that precedes group U+1's reads (all-waves guarantee).
__global__ __launch_bounds__(512, 2) void gemm_fused(
    const unsigned short* __restrict__ xb, const unsigned short* __restrict__ wb,
    const float* __restrict__ bzv, const float* __restrict__ bnv,
    unsigned short* __restrict__ Ab, unsigned short* __restrict__ Gb) {
  __shared__ unsigned short lds[2][4][8192];   // [buf][A0,A1,B0,B1][128*64]
  const int t = threadIdx.x;
  const int lane = t & 63;
  const int wid = t >> 6;             // 0..7
  const int wm = wid >> 2, wn = wid & 3;
  const int laneRow = lane & 15, lg = lane >> 4;

  // XCD-aware swizzle: 1024 wgs % 8 == 0 -> simple bijective form
  const int bid = blockIdx.x;
  const int swz = (bid & 7) * 128 + (bid >> 3);
  const int mtile = swz >> 4;         // 0..63
  const int ntile = swz & 15;         // 0..15 (consecutive share A-panel)

  const unsigned short* aBase = xb + (size_t)mtile * 256 * KDIM;
  const unsigned short* bBase = wb + (size_t)ntile * 256 * KDIM;

  // staging constants: thread t covers LDS chunks t and t+512 of a half-region
  const int r0 = t >> 3;              // row 0..63 (second load: +64)
  const int sSwz = (t & 7) ^ (r0 & 7);  // pre-swizzled global slot

#define STAGE(buf, reg, srcB, halfRow, kt) do {                                   \
    const unsigned short* s_ = (srcB) + (size_t)((halfRow) + r0) * KDIM           \
                               + (kt) * 64 + sSwz * 8;                            \
    unsigned short* d_ = &lds[buf][reg][t * 8];                                   \
    load_lds16(s_, d_);                                                           \
    load_lds16(s_ + 64 * KDIM, d_ + 4096);                                        \
  } while (0)

  // swizzled read slot offsets (shorts): slot = (ksub*4+lg) ^ (laneRow&7)
  const int sA0 = ((0 + lg) ^ (laneRow & 7)) * 8;
  const int sA1 = ((4 + lg) ^ (laneRow & 7)) * 8;
  const int bRow0 = (wn & 1) * 64;

  f32x4 acc[8][4] = {};

  // prologue: stage tile0 (all 4 halves) + tile1 B-halves; wait tile0 landed
  STAGE(0, 2, bBase, 0, 0);  STAGE(0, 3, bBase, 128, 0);
  STAGE(0, 0, aBase, 0, 0);  STAGE(0, 1, aBase, 128, 0);
  STAGE(1, 2, bBase, 0, 1);  STAGE(1, 3, bBase, 128, 1);
  asm volatile("s_waitcnt vmcnt(4)" ::: "memory");
  __builtin_amdgcn_sched_barrier(0);
  __builtin_amdgcn_s_barrier();

#define MFMA_QUAD(qm, qn)                                                         \
  _Pragma("unroll") for (int m = 0; m < 4; ++m)                                   \
  _Pragma("unroll") for (int n = 0; n < 2; ++n)                                   \
  _Pragma("unroll") for (int k = 0; k < 2; ++k)                                   \
    acc[(qm)*4 + m][(qn)*2 + n] = __builtin_amdgcn_mfma_f32_16x16x32_bf16(        \
        aF[m*2 + k], bF[((qn)*2 + n)*2 + k], acc[(qm)*4 + m][(qn)*2 + n], 0, 0, 0)

  for (int U = 0; U < NT; ++U) {
    const int cur = U & 1;
    const unsigned short* ldsA = lds[cur][wm];
    const unsigned short* ldsB = lds[cur][2 + (wn >> 1)];
    bf16x8 aF[8], bF[8];

    // ---- g1: quad(0,0) ----
#pragma unroll
    for (int m = 0; m < 4; ++m) {
      aF[m*2+0] = *(const bf16x8*)&ldsA[(m*16 + laneRow) * 64 + sA0];
      aF[m*2+1] = *(const bf16x8*)&ldsA[(m*16 + laneRow) * 64 + sA1];
    }
#pragma unroll
    for (int n = 0; n < 2; ++n) {
      bF[n*2+0] = *(const bf16x8*)&ldsB[(bRow0 + n*16 + laneRow) * 64 + sA0];
      bF[n*2+1] = *(const bf16x8*)&ldsB[(bRow0 + n*16 + laneRow) * 64 + sA1];
    }
    if (U + 1 < NT) STAGE(cur ^ 1, 0, aBase, 0, U + 1);
    __builtin_amdgcn_s_barrier();
    __builtin_amdgcn_s_setprio(1);
    MFMA_QUAD(0, 0);
    __builtin_amdgcn_s_setprio(0);
    __builtin_amdgcn_s_barrier();

    // ---- g2: quad(0,1) ----
#pragma unroll
    for (int n = 0; n < 2; ++n) {
      bF[4 + n*2+0] = *(const bf16x8*)&ldsB[(bRow0 + 32 + n*16 + laneRow) * 64 + sA0];
      bF[4 + n*2+1] = *(const bf16x8*)&ldsB[(bRow0 + 32 + n*16 + laneRow) * 64 + sA1];
    }
    if (U + 1 < NT) STAGE(cur ^ 1, 1, aBase, 128, U + 1);
    __builtin_amdgcn_s_barrier();
    __builtin_amdgcn_s_setprio(1);
    MFMA_QUAD(0, 1);
    __builtin_amdgcn_s_setprio(0);
    __builtin_amdgcn_s_barrier();

    // ---- g3: quad(1,0) ----
#pragma unroll
    for (int m = 0; m < 4; ++m) {
      aF[m*2+0] = *(const bf16x8*)&ldsA[(64 + m*16 + laneRow) * 64 + sA0];
      aF[m*2+1] = *(const bf16x8*)&ldsA[(64 + m*16 + laneRow) * 64 + sA1];
    }
    if (U + 2 < NT) STAGE(cur, 2, bBase, 0, U + 2);
    __builtin_amdgcn_s_barrier();
    __builtin_amdgcn_s_setprio(1);
    MFMA_QUAD(1, 0);
    __builtin_amdgcn_s_setprio(0);
    __builtin_amdgcn_s_barrier();

    // ---- g4: quad(1,1) ----
    if (U + 2 < NT) {
      STAGE(cur, 3, bBase, 128, U + 2);
      asm volatile("s_waitcnt vmcnt(4)" ::: "memory");   // tile U+1 landed
      __builtin_amdgcn_sched_barrier(0);
    } else if (U + 1 < NT) {
      asm volatile("s_waitcnt vmcnt(0)" ::: "memory");   // last prefetch landed
      __builtin_amdgcn_sched_barrier(0);
    }
    __builtin_amdgcn_s_barrier();
    __builtin_amdgcn_s_setprio(1);
    MFMA_QUAD(1, 1);
    __builtin_amdgcn_s_setprio(0);
    __builtin_amdgcn_s_barrier();
  }

  // ---- epilogue: bias + transform + bf16 store ----
  const int gcB = ntile * 256 + wn * 64;
  const int grB = mtile * 256 + wm * 128;
  const bool isZ = (ntile < 8);                // block-uniform
  unsigned short* outP = isZ ? Ab : Gb;
  float bias[4];
#pragma unroll
  for (int ni = 0; ni < 4; ++ni) {
    const int gc = gcB + ni * 16 + laneRow;
    bias[ni] = isZ ? bzv[gc] : bnv[gc - D_DIM];
  }
#pragma unroll
  for (int mi = 0; mi < 8; ++mi) {
#pragma unroll
    for (int ni = 0; ni < 4; ++ni) {
      const int gc = gcB + ni * 16 + laneRow;
      const int dcol = isZ ? gc : gc - D_DIM;
#pragma unroll
      for (int j = 0; j < 4; ++j) {
        const float val = acc[mi][ni][j] + bias[ni];
        const int gr = grB + mi * 16 + (lg << 2) + j;
        const size_t off = (size_t)gr * D_DIM + dcol;
        if (isZ) outP[off] = f2bf(1.0f / (1.0f + __expf(val)));
        else     outP[off] = f2bf(val >= 0.0f ? val + 0.5f
                                              : 1.0f / (1.0f + __expf(-val)));
      }
    }
  }
#undef STAGE
#undef MFMA_QUAD
}

// ---------------- blocked scan over L (2 channels per thread) ----------------
// pass1: per (b,chunk,dpair) compute (A,V) with h_end = A*h_start + V
__global__ __launch_bounds__(256) void scan_pass1(
    const unsigned short* __restrict__ Ab, const unsigned short* __restrict__ Gb,
    float* __restrict__ SA, float* __restrict__ SV) {
  const int tid = blockIdx.x * 256 + threadIdx.x;   // B*NCHUNK*D/2 = 262144
  const int dp = tid & 1023;                        // d = dp*2
  const int c = (tid >> 10) & (NCHUNK - 1);
  const int b = tid >> 16;
  const unsigned int* A32 = (const unsigned int*)Ab;
  const unsigned int* G32 = (const unsigned int*)Gb;
  size_t basePair = ((size_t)b * L_DIM + (size_t)c * CHUNK) * 1024 + dp;
  float A0 = 1.0f, V0 = 0.0f, A1 = 1.0f, V1 = 0.0f;
#pragma unroll 8
  for (int i = 0; i < CHUNK; ++i) {
    unsigned int av = A32[basePair + (size_t)i * 1024];
    unsigned int gv = G32[basePair + (size_t)i * 1024];
    float a0 = __uint_as_float(av << 16), a1 = __uint_as_float(av & 0xFFFF0000u);
    float g0 = __uint_as_float(gv << 16), g1 = __uint_as_float(gv & 0xFFFF0000u);
    V0 = a0 * V0 + (1.0f - a0) * g0;  A0 *= a0;
    V1 = a1 * V1 + (1.0f - a1) * g1;  A1 *= a1;
  }
  const size_t sidx = ((size_t)b * NCHUNK + c) * D_DIM + (size_t)dp * 2;
  *(float2*)&SA[sidx] = make_float2(A0, A1);
  *(float2*)&SV[sidx] = make_float2(V0, V1);
}

// pass2: sequential over chunks, store per-chunk starting h
__global__ __launch_bounds__(256) void scan_pass2(
    const float* __restrict__ SA, const float* __restrict__ SV,
    float* __restrict__ H0) {
  const int tid = blockIdx.x * 256 + threadIdx.x;   // B*D = 8192
  const int d = tid & (D_DIM - 1);
  const int b = tid >> 11;
  float h = 0.5f;
  for (int c = 0; c < NCHUNK; ++c) {
    size_t idx = ((size_t)b * NCHUNK + c) * D_DIM + d;
    H0[idx] = h;
    h = SA[idx] * h + SV[idx];
  }
}

// pass3: recompute within chunk from correct h_start, write fp32 output
__global__ __launch_bounds__(256) void scan_pass3(
    const unsigned short* __restrict__ Ab, const unsigned short* __restrict__ Gb,
    const float* __restrict__ H0, float* __restrict__ out) {
  const int tid = blockIdx.x * 256 + threadIdx.x;   // 262144
  const int dp = tid & 1023;
  const int c = (tid >> 10) & (NCHUNK - 1);
  const int b = tid >> 16;
  const unsigned int* A32 = (const unsigned int*)Ab;
  const unsigned int* G32 = (const unsigned int*)Gb;
  size_t basePair = ((size_t)b * L_DIM + (size_t)c * CHUNK) * 1024 + dp;
  const size_t hidx = ((size_t)b * NCHUNK + c) * D_DIM + (size_t)dp * 2;
  float2 h2 = *(const float2*)&H0[hidx];
  float h0 = h2.x, h1 = h2.y;
#pragma unroll 8
  for (int i = 0; i < CHUNK; ++i) {
    unsigned int av = A32[basePair + (size_t)i * 1024];
    unsigned int gv = G32[basePair + (size_t)i * 1024];
    float a0 = __uint_as_float(av << 16), a1 = __uint_as_float(av & 0xFFFF0000u);
    float g0 = __uint_as_float(gv << 16), g1 = __uint_as_float(gv & 0xFFFF0000u);
    h0 = a0 * h0 + (1.0f - a0) * g0;
    h1 = a1 * h1 + (1.0f - a1) * g1;
    *(float2*)&out[(basePair + (size_t)i * 1024) * 2] = make_float2(h0, h1);
  }
}

extern "C" void kernel_launch(void* const* d_in, const int* in_sizes, int n_in,
                              void* d_out, int out_size, void* d_ws, size_t ws_size,
                              hipStream_t stream) {
  const float* x  = (const float*)d_in[0];
  const float* Wz = (const float*)d_in[1];
  const float* bz = (const float*)d_in[2];
  const float* Wn = (const float*)d_in[3];
  const float* bn = (const float*)d_in[4];
  float* out = (float*)d_out;

  char* ws = (char*)d_ws;
  // workspace layout (total ~224.4 MB)
  unsigned short* xb = (unsigned short*)(ws);                       // 67108864 B
  unsigned short* wb = (unsigned short*)(ws + 67108864);            // 16777216 B
  unsigned short* Ab = (unsigned short*)(ws + 83886080);            // 67108864 B
  unsigned short* Gb = (unsigned short*)(ws + 150994944);           // 67108864 B
  float* SA = (float*)(ws + 218103808);                             // 2097152 B
  float* SV = (float*)(ws + 220200960);                             // 2097152 B
  float* H0 = (float*)(ws + 222298112);                             // 2097152 B

  cast_inputs<<<40960, 256, 0, stream>>>(x, Wz, Wn, xb, wb);
  gemm_fused<<<1024, 512, 0, stream>>>(xb, wb, bz, bn, Ab, Gb);
  scan_pass1<<<1024, 256, 0, stream>>>(Ab, Gb, SA, SV);
  scan_pass2<<<32, 256, 0, stream>>>(SA, SV, H0);
  scan_pass3<<<1024, 256, 0, stream>>>(Ab, Gb, H0, out);
}